// Round 14
// baseline (38.844 us; speedup 1.0000x reference)
//
#include <hip/hip_runtime.h>
#include <math.h>

constexpr int B = 16, H = 16, KVH = 4, D = 128;
constexpr int BLK = 16, MAXB = 256;
constexpr int GRP = H / KVH;     // 4 query heads per KV head
constexpr int NSL = 16;          // slices per (b,hkv); slice s owns union idx s, s+NSL, ...
constexpr int MAXCNT = 9;        // ceil(144/16)
constexpr int WSTRIDE = D + 2;   // per-(slice,head) partial: o[128], m, s

// Layout closed form (validated R7-R13): head h attends kb iff pbid-kb<32 or kb%8==h%8.
// Group hkv: phases p..p+3, p=(hkv&1)*4. Union = strided [0,M) prefix-valid
// (kb=8*(i>>2)+p+(i&3), mask=1<<(i&3), kb strictly monotone) + local [M,pbid] (mask 15).

__global__ __launch_bounds__(256) void sparse_attn_slice(
    const float* __restrict__ q,            // (B,H,D)
    const float* __restrict__ k_cache,      // (NB,KVH,32,16,4)
    const float* __restrict__ v_cache,      // (NB,KVH,128,16)
    const int* __restrict__ block_tables,   // (B,MAXB)
    const int* __restrict__ context_lens,   // (B,)
    float* __restrict__ wsB)
{
    const int wg = blockIdx.x;
    const int gidx = wg >> 4, slice = wg & (NSL - 1);
    const int b = gidx >> 2, hkv = gidx & 3;
    const int tid = threadIdx.x;
    const int lane = tid & 63;
    const int wv = tid >> 6;                // 0..3

    const int q_pid = context_lens[b] - 1;
    const int pbid = q_pid >> 4;
    const int p = (hkv & 1) * 4;
    const int M = max(0, pbid - 31);        // strided region = [0, M)
    int nstr = 0;
    #pragma unroll
    for (int u = 0; u < 4; ++u) {
        const int dd = M - p - u;
        nstr += (dd > 0) ? ((dd + 7) >> 3) : 0;
    }
    const int U = nstr + (pbid - M + 1);
    const int cnt = (slice < U) ? ((U - 1 - slice) / NSL + 1) : 0;   // <= 9

    float* pb = wsB + (size_t)((gidx * NSL + slice) * GRP) * WSTRIDE;
    if (cnt == 0) {                         // must still write (ws poisoned)
        for (int i = tid; i < GRP * WSTRIDE; i += 256)
            pb[i] = ((i % WSTRIDE) == D) ? -INFINITY : 0.f;
        return;
    }

    __shared__ float s_q[GRP * D];              // 2 KB
    __shared__ float s_p[GRP][MAXCNT * BLK];    // raw(masked) scores then probs
    __shared__ int   s_col[MAXCNT], s_msk[MAXCNT], s_bt[MAXCNT];
    __shared__ float s_redm[GRP][4];
    __shared__ float s_m[GRP], s_s[GRP];

    if (tid < 128)
        ((float4*)s_q)[tid] = ((const float4*)(q + (size_t)(b * H + hkv * GRP) * D))[tid];
    if (tid < MAXCNT) {
        const int i = min(slice + tid * NSL, U - 1);   // clamped: always a valid entry
        int kb, mk;
        if (i < nstr) { kb = ((i >> 2) << 3) + p + (i & 3); mk = 1 << (i & 3); }
        else          { kb = M + (i - nstr);                mk = 15; }
        s_col[tid] = kb;
        s_msk[tid] = (tid < cnt) ? mk : 0;
        s_bt[tid]  = block_tables[b * MAXB + kb];
    }
    __syncthreads();

    const float sm_scale = 0.08838834764831845f; // 1/sqrt(128)
    const float4* q4 = (const float4*)s_q;

    // ---- scores: wave per block; lane = (n, dq); 8 float4 per lane
    const int n  = (lane >> 2) & 15;
    const int dq = lane & 3;
    {
        float mx[GRP] = {-INFINITY, -INFINITY, -INFINITY, -INFINITY};
        for (int j = wv; j < cnt; j += 4) {
            const int pos = s_col[j] * BLK + n;  // uniform across the dq-quad
            float sc[GRP];
            if (pos <= q_pid) {
                const float4* kp = (const float4*)(k_cache + (size_t)(s_bt[j] * KVH + hkv) * (D * BLK));
                float acc[GRP] = {0.f, 0.f, 0.f, 0.f};
                #pragma unroll
                for (int i = 0; i < 8; ++i) {
                    const int d1 = dq * 8 + i;
                    const float4 kv = kp[d1 * 16 + n];
                    #pragma unroll
                    for (int g = 0; g < GRP; ++g) {
                        const float4 qv = q4[g * 32 + d1];
                        acc[g] += kv.x * qv.x + kv.y * qv.y + kv.z * qv.z + kv.w * qv.w;
                    }
                }
                const int mk = s_msk[j];
                #pragma unroll
                for (int g = 0; g < GRP; ++g) {
                    float a = acc[g];
                    a += __shfl_xor(a, 1);
                    a += __shfl_xor(a, 2);   // full dot on all 4 dq lanes
                    sc[g] = ((mk >> g) & 1) ? a * sm_scale : -INFINITY;
                }
            } else {
                #pragma unroll
                for (int g = 0; g < GRP; ++g) sc[g] = -INFINITY;
            }
            if (dq == 0) {
                #pragma unroll
                for (int g = 0; g < GRP; ++g) s_p[g][j * 16 + n] = sc[g];
            }
            #pragma unroll
            for (int g = 0; g < GRP; ++g) mx[g] = fmaxf(mx[g], sc[g]);
        }
        #pragma unroll
        for (int g = 0; g < GRP; ++g) {
            float v = mx[g];
            #pragma unroll
            for (int off = 1; off < 64; off <<= 1)
                v = fmaxf(v, __shfl_xor(v, off));
            if (lane == 0) s_redm[g][wv] = v;
        }
    }

    // ---- V prefetch: issue V loads for exactly cnt blocks (wave-uniform break
    // keeps the unroll static). Thread owns d = tid/2, token half dh = tid&1.
    float4 vr0[MAXCNT], vr1[MAXCNT];
    #pragma unroll
    for (int jj = 0; jj < MAXCNT; ++jj) {
        if (jj >= cnt) break;
        const float4* vp = (const float4*)(v_cache + (size_t)(s_bt[jj] * KVH + hkv) * (D * BLK));
        vr0[jj] = vp[tid * 2];
        vr1[jj] = vp[tid * 2 + 1];
    }
    __syncthreads();   // drains V loads + publishes s_p/s_redm

    // ---- softmax: wave g owns head g; zero-pad probs to MAXCNT*BLK
    {
        const int g = wv;
        const int tot = cnt * BLK;
        const float mg = fmaxf(fmaxf(s_redm[g][0], s_redm[g][1]),
                               fmaxf(s_redm[g][2], s_redm[g][3]));
        float sum = 0.f;
        #pragma unroll
        for (int t = 0; t < 3; ++t) {       // 3*64 = 192 >= 144
            const int e = lane + 64 * t;
            float pe = 0.f;
            if (e < tot) {
                const float v = s_p[g][e];
                pe = (v == -INFINITY) ? 0.f : __expf(v - mg);
            }
            if (e < MAXCNT * BLK) s_p[g][e] = pe;
            sum += pe;
        }
        #pragma unroll
        for (int off = 1; off < 64; off <<= 1)
            sum += __shfl_xor(sum, off);
        if (lane == 0) { s_m[g] = mg; s_s[g] = sum; }
    }
    __syncthreads();

    // ---- PV: pure FMA, unrolled with wave-uniform break at cnt
    {
        const int dh = tid & 1;
        float acc[GRP] = {0.f, 0.f, 0.f, 0.f};
        #pragma unroll
        for (int jj = 0; jj < MAXCNT; ++jj) {
            if (jj >= cnt) break;
            const float4 v0 = vr0[jj], v1 = vr1[jj];
            #pragma unroll
            for (int g = 0; g < GRP; ++g) {
                const float4 p0 = ((const float4*)&s_p[g][jj * BLK])[dh * 2];
                const float4 p1 = ((const float4*)&s_p[g][jj * BLK])[dh * 2 + 1];
                acc[g] += v0.x * p0.x + v0.y * p0.y + v0.z * p0.z + v0.w * p0.w
                        + v1.x * p1.x + v1.y * p1.y + v1.z * p1.z + v1.w * p1.w;
            }
        }
        #pragma unroll
        for (int g = 0; g < GRP; ++g)
            acc[g] += __shfl_xor(acc[g], 1);
        if (dh == 0) {
            #pragma unroll
            for (int g = 0; g < GRP; ++g)
                pb[g * WSTRIDE + (tid >> 1)] = acc[g];
        }
        if (tid == 0) {
            #pragma unroll
            for (int g = 0; g < GRP; ++g) {
                pb[g * WSTRIDE + D]     = s_m[g];
                pb[g * WSTRIDE + D + 1] = s_s[g];
            }
        }
    }
}

// ---------------- combine: LSE-merge NSL slices per (b,h) ----------------
__global__ __launch_bounds__(128) void sparse_attn_combine(
    const float* __restrict__ wsB,
    float* __restrict__ out)
{
    const int bh = blockIdx.x;              // b*H + h
    const int h = bh & (H - 1);
    const int gidx = (bh >> 4) * 4 + (h >> 2);
    const int g = h & 3;
    const int d = threadIdx.x;

    const float* base = wsB + (size_t)(gidx * NSL * GRP + g) * WSTRIDE;

    float m = -INFINITY;
    #pragma unroll
    for (int s = 0; s < NSL; ++s)
        m = fmaxf(m, base[s * GRP * WSTRIDE + D]);

    float num = 0.f, den = 0.f;
    #pragma unroll
    for (int s = 0; s < NSL; ++s) {
        const float ms = base[s * GRP * WSTRIDE + D];
        const float ss = base[s * GRP * WSTRIDE + D + 1];
        const float a = (ms == -INFINITY) ? 0.f : __expf(ms - m);
        num += base[s * GRP * WSTRIDE + d] * a;
        den += ss * a;
    }
    out[bh * D + d] = num / den;
}

extern "C" void kernel_launch(void* const* d_in, const int* in_sizes, int n_in,
                              void* d_out, int out_size, void* d_ws, size_t ws_size,
                              hipStream_t stream) {
    const float* q            = (const float*)d_in[0];
    const float* k_cache      = (const float*)d_in[1];
    const float* v_cache      = (const float*)d_in[2];
    const int*   block_tables = (const int*)d_in[3];
    const int*   context_lens = (const int*)d_in[4];
    float* out = (float*)d_out;
    float* wsB = (float*)d_ws;

    sparse_attn_slice<<<B * KVH * NSL, 256, 0, stream>>>(
        q, k_cache, v_cache, block_tables, context_lens, wsB);
    sparse_attn_combine<<<B * H, 128, 0, stream>>>(wsB, out);
}

// Round 15
// 29.306 us; speedup vs baseline: 1.3255x; 1.3255x over previous
//
#include <hip/hip_runtime.h>
#include <math.h>

constexpr int B = 16, H = 16, KVH = 4, D = 128;
constexpr int BLK = 16, MAXB = 256;
constexpr int GRP = H / KVH;     // 4 query heads per KV head
constexpr int NSL = 16;          // slices per (b,hkv); slice s owns union idx s, s+NSL, ...
constexpr int MAXCNT = 9;        // ceil(144/16)
constexpr int WSTRIDE = D + 2;   // per-(slice,head) partial: o[128], m, s

// Layout closed form (validated R7-R14): head h attends kb iff pbid-kb<32 or kb%8==h%8.
// Group hkv: phases p..p+3, p=(hkv&1)*4. Union = strided [0,M) prefix-valid
// (kb=8*(i>>2)+p+(i&3), mask=1<<(i&3), kb strictly monotone) + local [M,pbid] (mask 15).

__global__ __launch_bounds__(256) void sparse_attn_slice(
    const float* __restrict__ q,            // (B,H,D)
    const float* __restrict__ k_cache,      // (NB,KVH,32,16,4)
    const float* __restrict__ v_cache,      // (NB,KVH,128,16)
    const int* __restrict__ block_tables,   // (B,MAXB)
    const int* __restrict__ context_lens,   // (B,)
    float* __restrict__ wsB)
{
    const int wg = blockIdx.x;
    const int gidx = wg >> 4, slice = wg & (NSL - 1);
    const int b = gidx >> 2, hkv = gidx & 3;
    const int tid = threadIdx.x;
    const int lane = tid & 63;
    const int wv = tid >> 6;                // 0..3

    const int q_pid = context_lens[b] - 1;
    const int pbid = q_pid >> 4;
    const int p = (hkv & 1) * 4;
    const int M = max(0, pbid - 31);        // strided region = [0, M)
    int nstr = 0;
    #pragma unroll
    for (int u = 0; u < 4; ++u) {
        const int dd = M - p - u;
        nstr += (dd > 0) ? ((dd + 7) >> 3) : 0;
    }
    const int U = nstr + (pbid - M + 1);
    const int cnt = (slice < U) ? ((U - 1 - slice) / NSL + 1) : 0;   // <= 9

    float* pb = wsB + (size_t)((gidx * NSL + slice) * GRP) * WSTRIDE;
    if (cnt == 0) {                         // must still write (ws poisoned)
        for (int i = tid; i < GRP * WSTRIDE; i += 256)
            pb[i] = ((i % WSTRIDE) == D) ? -INFINITY : 0.f;
        return;
    }

    __shared__ float s_q[GRP * D];              // 2 KB
    __shared__ float s_p[GRP][MAXCNT * BLK];    // raw(masked) scores then probs
    __shared__ int   s_col[MAXCNT], s_msk[MAXCNT], s_bt[MAXCNT];
    __shared__ float s_redm[GRP][4];
    __shared__ float s_m[GRP], s_s[GRP];

    if (tid < 128)
        ((float4*)s_q)[tid] = ((const float4*)(q + (size_t)(b * H + hkv * GRP) * D))[tid];
    if (tid < MAXCNT) {
        const int i = min(slice + tid * NSL, U - 1);   // clamped: always a valid entry
        int kb, mk;
        if (i < nstr) { kb = ((i >> 2) << 3) + p + (i & 3); mk = 1 << (i & 3); }
        else          { kb = M + (i - nstr);                mk = 15; }
        s_col[tid] = kb;
        s_msk[tid] = (tid < cnt) ? mk : 0;   // mask 0 for padded entries
        s_bt[tid]  = block_tables[b * MAXB + kb];
    }
    __syncthreads();

    const float sm_scale = 0.08838834764831845f; // 1/sqrt(128)
    const float4* q4 = (const float4*)s_q;

    // ---- scores: wave handles j=wv and j=wv+4 CONCURRENTLY (16 K-float4 in
    // flight instead of 8); padded j's are clamped-valid + mask 0.
    const int n  = (lane >> 2) & 15;
    const int dq = lane & 3;
    {
        const int j0 = wv, j1 = wv + 4;      // both < MAXCNT=9; s_bt valid, s_msk 0-padded
        const float4* kp0 = (const float4*)(k_cache + (size_t)(s_bt[j0] * KVH + hkv) * (D * BLK));
        const float4* kp1 = (const float4*)(k_cache + (size_t)(s_bt[j1] * KVH + hkv) * (D * BLK));
        float4 ka[8], kbf[8];
        #pragma unroll
        for (int i = 0; i < 8; ++i) {
            const int idx = (dq * 8 + i) * 16 + n;
            ka[i]  = kp0[idx];
            kbf[i] = kp1[idx];
        }
        float acc0[GRP] = {0.f, 0.f, 0.f, 0.f};
        float acc1[GRP] = {0.f, 0.f, 0.f, 0.f};
        #pragma unroll
        for (int i = 0; i < 8; ++i) {
            const int d1 = dq * 8 + i;
            #pragma unroll
            for (int g = 0; g < GRP; ++g) {
                const float4 qv = q4[g * 32 + d1];
                acc0[g] += ka[i].x * qv.x + ka[i].y * qv.y + ka[i].z * qv.z + ka[i].w * qv.w;
                acc1[g] += kbf[i].x * qv.x + kbf[i].y * qv.y + kbf[i].z * qv.z + kbf[i].w * qv.w;
            }
        }
        const int pos0 = s_col[j0] * BLK + n;
        const int pos1 = s_col[j1] * BLK + n;
        const int mk0 = s_msk[j0], mk1 = s_msk[j1];
        float mx[GRP];
        #pragma unroll
        for (int g = 0; g < GRP; ++g) {
            float a0 = acc0[g];
            a0 += __shfl_xor(a0, 1);
            a0 += __shfl_xor(a0, 2);
            float a1 = acc1[g];
            a1 += __shfl_xor(a1, 1);
            a1 += __shfl_xor(a1, 2);
            const float sc0 = (((mk0 >> g) & 1) && pos0 <= q_pid) ? a0 * sm_scale : -INFINITY;
            const float sc1 = (((mk1 >> g) & 1) && pos1 <= q_pid) ? a1 * sm_scale : -INFINITY;
            if (dq == 0) {
                s_p[g][j0 * 16 + n] = sc0;
                s_p[g][j1 * 16 + n] = sc1;
            }
            mx[g] = fmaxf(sc0, sc1);
        }
        // tail: j=8 (only when cnt==9), wave 0 only
        if (wv == 0 && 8 < cnt) {
            const int j2 = 8;
            const int pos2 = s_col[j2] * BLK + n;
            const float4* kp2 = (const float4*)(k_cache + (size_t)(s_bt[j2] * KVH + hkv) * (D * BLK));
            float acc2[GRP] = {0.f, 0.f, 0.f, 0.f};
            #pragma unroll
            for (int i = 0; i < 8; ++i) {
                const int d1 = dq * 8 + i;
                const float4 kv = kp2[(d1) * 16 + n];
                #pragma unroll
                for (int g = 0; g < GRP; ++g) {
                    const float4 qv = q4[g * 32 + d1];
                    acc2[g] += kv.x * qv.x + kv.y * qv.y + kv.z * qv.z + kv.w * qv.w;
                }
            }
            const int mk2 = s_msk[j2];
            #pragma unroll
            for (int g = 0; g < GRP; ++g) {
                float a2 = acc2[g];
                a2 += __shfl_xor(a2, 1);
                a2 += __shfl_xor(a2, 2);
                const float sc2 = (((mk2 >> g) & 1) && pos2 <= q_pid) ? a2 * sm_scale : -INFINITY;
                if (dq == 0) s_p[g][j2 * 16 + n] = sc2;
                mx[g] = fmaxf(mx[g], sc2);
            }
        } else if (wv == 0) {
            // ensure j=8 slot holds -inf scores when unused but cnt<=8: softmax
            // only reads e < cnt*16, and zero-pads the rest -- nothing needed.
        }
        #pragma unroll
        for (int g = 0; g < GRP; ++g) {
            float v = mx[g];
            #pragma unroll
            for (int off = 1; off < 64; off <<= 1)
                v = fmaxf(v, __shfl_xor(v, off));
            if (lane == 0) s_redm[g][wv] = v;
        }
    }

    // ---- V prefetch (R11-proven position/pattern): all MAXCNT blocks, clamped.
    // Thread owns d = tid/2, token half dh = tid&1. Duplicated tails are L2 hits.
    float4 vr0[MAXCNT], vr1[MAXCNT];
    #pragma unroll
    for (int jj = 0; jj < MAXCNT; ++jj) {
        const int jc = (jj < cnt) ? jj : cnt - 1;
        const float4* vp = (const float4*)(v_cache + (size_t)(s_bt[jc] * KVH + hkv) * (D * BLK));
        vr0[jj] = vp[tid * 2];
        vr1[jj] = vp[tid * 2 + 1];
    }
    __syncthreads();   // drains V loads + publishes s_p/s_redm

    // ---- softmax: wave g owns head g; zero-pad probs to MAXCNT*BLK
    {
        const int g = wv;
        const int tot = cnt * BLK;
        const float mg = fmaxf(fmaxf(s_redm[g][0], s_redm[g][1]),
                               fmaxf(s_redm[g][2], s_redm[g][3]));
        float sum = 0.f;
        #pragma unroll
        for (int t = 0; t < 3; ++t) {       // 3*64 = 192 >= 144
            const int e = lane + 64 * t;
            float pe = 0.f;
            if (e < tot) {
                const float v = s_p[g][e];
                pe = (v == -INFINITY) ? 0.f : __expf(v - mg);
            }
            if (e < MAXCNT * BLK) s_p[g][e] = pe;
            sum += pe;
        }
        #pragma unroll
        for (int off = 1; off < 64; off <<= 1)
            sum += __shfl_xor(sum, off);
        if (lane == 0) { s_m[g] = mg; s_s[g] = sum; }
    }
    __syncthreads();

    // ---- PV: pure FMA, fully unrolled; probs are zero for jj >= cnt
    {
        const int dh = tid & 1;
        float acc[GRP] = {0.f, 0.f, 0.f, 0.f};
        #pragma unroll
        for (int jj = 0; jj < MAXCNT; ++jj) {
            const float4 v0 = vr0[jj], v1 = vr1[jj];
            #pragma unroll
            for (int g = 0; g < GRP; ++g) {
                const float4 p0 = ((const float4*)&s_p[g][jj * BLK])[dh * 2];
                const float4 p1 = ((const float4*)&s_p[g][jj * BLK])[dh * 2 + 1];
                acc[g] += v0.x * p0.x + v0.y * p0.y + v0.z * p0.z + v0.w * p0.w
                        + v1.x * p1.x + v1.y * p1.y + v1.z * p1.z + v1.w * p1.w;
            }
        }
        #pragma unroll
        for (int g = 0; g < GRP; ++g)
            acc[g] += __shfl_xor(acc[g], 1);
        if (dh == 0) {
            #pragma unroll
            for (int g = 0; g < GRP; ++g)
                pb[g * WSTRIDE + (tid >> 1)] = acc[g];
        }
        if (tid == 0) {
            #pragma unroll
            for (int g = 0; g < GRP; ++g) {
                pb[g * WSTRIDE + D]     = s_m[g];
                pb[g * WSTRIDE + D + 1] = s_s[g];
            }
        }
    }
}

// ---------------- combine: LSE-merge NSL slices per (b,h) ----------------
__global__ __launch_bounds__(128) void sparse_attn_combine(
    const float* __restrict__ wsB,
    float* __restrict__ out)
{
    const int bh = blockIdx.x;              // b*H + h
    const int h = bh & (H - 1);
    const int gidx = (bh >> 4) * 4 + (h >> 2);
    const int g = h & 3;
    const int d = threadIdx.x;

    const float* base = wsB + (size_t)(gidx * NSL * GRP + g) * WSTRIDE;

    float m = -INFINITY;
    #pragma unroll
    for (int s = 0; s < NSL; ++s)
        m = fmaxf(m, base[s * GRP * WSTRIDE + D]);

    float num = 0.f, den = 0.f;
    #pragma unroll
    for (int s = 0; s < NSL; ++s) {
        const float ms = base[s * GRP * WSTRIDE + D];
        const float ss = base[s * GRP * WSTRIDE + D + 1];
        const float a = (ms == -INFINITY) ? 0.f : __expf(ms - m);
        num += base[s * GRP * WSTRIDE + d] * a;
        den += ss * a;
    }
    out[bh * D + d] = num / den;
}

extern "C" void kernel_launch(void* const* d_in, const int* in_sizes, int n_in,
                              void* d_out, int out_size, void* d_ws, size_t ws_size,
                              hipStream_t stream) {
    const float* q            = (const float*)d_in[0];
    const float* k_cache      = (const float*)d_in[1];
    const float* v_cache      = (const float*)d_in[2];
    const int*   block_tables = (const int*)d_in[3];
    const int*   context_lens = (const int*)d_in[4];
    float* out = (float*)d_out;
    float* wsB = (float*)d_ws;

    sparse_attn_slice<<<B * KVH * NSL, 256, 0, stream>>>(
        q, k_cache, v_cache, block_tables, context_lens, wsB);
    sparse_attn_combine<<<B * H, 128, 0, stream>>>(wsB, out);
}

// Round 16
// 26.451 us; speedup vs baseline: 1.4685x; 1.1079x over previous
//
#include <hip/hip_runtime.h>
#include <math.h>

constexpr int B = 16, H = 16, KVH = 4, D = 128;
constexpr int BLK = 16, MAXB = 256;
constexpr int GRP = H / KVH;     // 4 query heads per KV head
constexpr int NSL = 16;          // slices per (b,hkv); slice s owns union idx s, s+NSL, ...
constexpr int MAXCNT = 9;        // ceil(144/16)
constexpr int WSTRIDE = D + 2;   // per-(slice,head) partial: o[128], m, s

// Layout closed form (validated R7-R15): head h attends kb iff pbid-kb<32 or kb%8==h%8.
// Group hkv: phases p..p+3, p=(hkv&1)*4. Union = strided [0,M) prefix-valid
// (kb=8*(i>>2)+p+(i&3), mask=1<<(i&3), kb strictly monotone) + local [M,pbid] (mask 15).

// __launch_bounds__(256, 4): grid supplies only 4 WGs/CU (= 4 waves/SIMD), so
// allow the allocator 128 VGPR instead of the 56 it picks when chasing 8 w/SIMD
// (R12 PMC evidence). 128 VGPR still sustains 4 waves/SIMD (m69) -> free ILP.
__global__ __launch_bounds__(256, 4) void sparse_attn_slice(
    const float* __restrict__ q,            // (B,H,D)
    const float* __restrict__ k_cache,      // (NB,KVH,32,16,4)
    const float* __restrict__ v_cache,      // (NB,KVH,128,16)
    const int* __restrict__ block_tables,   // (B,MAXB)
    const int* __restrict__ context_lens,   // (B,)
    float* __restrict__ wsB)
{
    const int wg = blockIdx.x;
    const int gidx = wg >> 4, slice = wg & (NSL - 1);
    const int b = gidx >> 2, hkv = gidx & 3;
    const int tid = threadIdx.x;
    const int lane = tid & 63;
    const int wv = tid >> 6;                // 0..3

    const int q_pid = context_lens[b] - 1;
    const int pbid = q_pid >> 4;
    const int p = (hkv & 1) * 4;
    const int M = max(0, pbid - 31);        // strided region = [0, M)
    int nstr = 0;
    #pragma unroll
    for (int u = 0; u < 4; ++u) {
        const int dd = M - p - u;
        nstr += (dd > 0) ? ((dd + 7) >> 3) : 0;
    }
    const int U = nstr + (pbid - M + 1);
    const int cnt = (slice < U) ? ((U - 1 - slice) / NSL + 1) : 0;   // <= 9

    float* pb = wsB + (size_t)((gidx * NSL + slice) * GRP) * WSTRIDE;
    if (cnt == 0) {                         // must still write (ws poisoned)
        for (int i = tid; i < GRP * WSTRIDE; i += 256)
            pb[i] = ((i % WSTRIDE) == D) ? -INFINITY : 0.f;
        return;
    }

    __shared__ float s_q[GRP * D];              // 2 KB
    __shared__ float s_p[GRP][MAXCNT * BLK];    // raw(masked) scores then probs
    __shared__ int   s_col[MAXCNT], s_msk[MAXCNT], s_bt[MAXCNT];
    __shared__ float s_redm[GRP][4];
    __shared__ float s_m[GRP], s_s[GRP];

    if (tid < 128)
        ((float4*)s_q)[tid] = ((const float4*)(q + (size_t)(b * H + hkv * GRP) * D))[tid];
    if (tid < MAXCNT) {
        const int i = min(slice + tid * NSL, U - 1);   // clamped: always a valid entry
        int kb, mk;
        if (i < nstr) { kb = ((i >> 2) << 3) + p + (i & 3); mk = 1 << (i & 3); }
        else          { kb = M + (i - nstr);                mk = 15; }
        s_col[tid] = kb;
        s_msk[tid] = (tid < cnt) ? mk : 0;
        s_bt[tid]  = block_tables[b * MAXB + kb];
    }
    __syncthreads();

    const float sm_scale = 0.08838834764831845f; // 1/sqrt(128)
    const float4* q4 = (const float4*)s_q;

    // ---- scores: wave per block; lane = (n, dq); 8 float4 per lane
    const int n  = (lane >> 2) & 15;
    const int dq = lane & 3;
    {
        float mx[GRP] = {-INFINITY, -INFINITY, -INFINITY, -INFINITY};
        for (int j = wv; j < cnt; j += 4) {
            const int pos = s_col[j] * BLK + n;  // uniform across the dq-quad
            float sc[GRP];
            if (pos <= q_pid) {
                const float4* kp = (const float4*)(k_cache + (size_t)(s_bt[j] * KVH + hkv) * (D * BLK));
                float acc[GRP] = {0.f, 0.f, 0.f, 0.f};
                #pragma unroll
                for (int i = 0; i < 8; ++i) {
                    const int d1 = dq * 8 + i;
                    const float4 kv = kp[d1 * 16 + n];
                    #pragma unroll
                    for (int g = 0; g < GRP; ++g) {
                        const float4 qv = q4[g * 32 + d1];
                        acc[g] += kv.x * qv.x + kv.y * qv.y + kv.z * qv.z + kv.w * qv.w;
                    }
                }
                const int mk = s_msk[j];
                #pragma unroll
                for (int g = 0; g < GRP; ++g) {
                    float a = acc[g];
                    a += __shfl_xor(a, 1);
                    a += __shfl_xor(a, 2);   // full dot on all 4 dq lanes
                    sc[g] = ((mk >> g) & 1) ? a * sm_scale : -INFINITY;
                }
            } else {
                #pragma unroll
                for (int g = 0; g < GRP; ++g) sc[g] = -INFINITY;
            }
            if (dq == 0) {
                #pragma unroll
                for (int g = 0; g < GRP; ++g) s_p[g][j * 16 + n] = sc[g];
            }
            #pragma unroll
            for (int g = 0; g < GRP; ++g) mx[g] = fmaxf(mx[g], sc[g]);
        }
        #pragma unroll
        for (int g = 0; g < GRP; ++g) {
            float v = mx[g];
            #pragma unroll
            for (int off = 1; off < 64; off <<= 1)
                v = fmaxf(v, __shfl_xor(v, off));
            if (lane == 0) s_redm[g][wv] = v;
        }
    }

    // ---- V prefetch: ALL V loads issued now, unconditionally (clamped index).
    // Thread owns d = tid/2, token half dh = tid&1.
    float4 vr0[MAXCNT], vr1[MAXCNT];
    #pragma unroll
    for (int jj = 0; jj < MAXCNT; ++jj) {
        const int jc = (jj < cnt) ? jj : cnt - 1;    // safe dup of last block
        const float4* vp = (const float4*)(v_cache + (size_t)(s_bt[jc] * KVH + hkv) * (D * BLK));
        vr0[jj] = vp[tid * 2];
        vr1[jj] = vp[tid * 2 + 1];
    }
    __syncthreads();   // drains all 18 in-flight V loads + publishes s_p/s_redm

    // ---- softmax: wave g owns head g; zero-pad probs to MAXCNT*BLK
    {
        const int g = wv;
        const int tot = cnt * BLK;
        const float mg = fmaxf(fmaxf(s_redm[g][0], s_redm[g][1]),
                               fmaxf(s_redm[g][2], s_redm[g][3]));
        float sum = 0.f;
        #pragma unroll
        for (int t = 0; t < 3; ++t) {       // 3*64 = 192 >= 144
            const int e = lane + 64 * t;
            float pe = 0.f;
            if (e < tot) {
                const float v = s_p[g][e];
                pe = (v == -INFINITY) ? 0.f : __expf(v - mg);
            }
            if (e < MAXCNT * BLK) s_p[g][e] = pe;
            sum += pe;
        }
        #pragma unroll
        for (int off = 1; off < 64; off <<= 1)
            sum += __shfl_xor(sum, off);
        if (lane == 0) { s_m[g] = mg; s_s[g] = sum; }
    }
    __syncthreads();

    // ---- PV: pure FMA, fully unrolled; probs are zero for jj >= cnt
    {
        const int dh = tid & 1;
        float acc[GRP] = {0.f, 0.f, 0.f, 0.f};
        #pragma unroll
        for (int jj = 0; jj < MAXCNT; ++jj) {
            const float4 v0 = vr0[jj], v1 = vr1[jj];
            #pragma unroll
            for (int g = 0; g < GRP; ++g) {
                const float4 p0 = ((const float4*)&s_p[g][jj * BLK])[dh * 2];
                const float4 p1 = ((const float4*)&s_p[g][jj * BLK])[dh * 2 + 1];
                acc[g] += v0.x * p0.x + v0.y * p0.y + v0.z * p0.z + v0.w * p0.w
                        + v1.x * p1.x + v1.y * p1.y + v1.z * p1.z + v1.w * p1.w;
            }
        }
        #pragma unroll
        for (int g = 0; g < GRP; ++g)
            acc[g] += __shfl_xor(acc[g], 1);
        if (dh == 0) {
            #pragma unroll
            for (int g = 0; g < GRP; ++g)
                pb[g * WSTRIDE + (tid >> 1)] = acc[g];
        }
        if (tid == 0) {
            #pragma unroll
            for (int g = 0; g < GRP; ++g) {
                pb[g * WSTRIDE + D]     = s_m[g];
                pb[g * WSTRIDE + D + 1] = s_s[g];
            }
        }
    }
}

// ---------------- combine: LSE-merge NSL slices per (b,h) ----------------
__global__ __launch_bounds__(128) void sparse_attn_combine(
    const float* __restrict__ wsB,
    float* __restrict__ out)
{
    const int bh = blockIdx.x;              // b*H + h
    const int h = bh & (H - 1);
    const int gidx = (bh >> 4) * 4 + (h >> 2);
    const int g = h & 3;
    const int d = threadIdx.x;

    const float* base = wsB + (size_t)(gidx * NSL * GRP + g) * WSTRIDE;

    float m = -INFINITY;
    #pragma unroll
    for (int s = 0; s < NSL; ++s)
        m = fmaxf(m, base[s * GRP * WSTRIDE + D]);

    float num = 0.f, den = 0.f;
    #pragma unroll
    for (int s = 0; s < NSL; ++s) {
        const float ms = base[s * GRP * WSTRIDE + D];
        const float ss = base[s * GRP * WSTRIDE + D + 1];
        const float a = (ms == -INFINITY) ? 0.f : __expf(ms - m);
        num += base[s * GRP * WSTRIDE + d] * a;
        den += ss * a;
    }
    out[bh * D + d] = num / den;
}

extern "C" void kernel_launch(void* const* d_in, const int* in_sizes, int n_in,
                              void* d_out, int out_size, void* d_ws, size_t ws_size,
                              hipStream_t stream) {
    const float* q            = (const float*)d_in[0];
    const float* k_cache      = (const float*)d_in[1];
    const float* v_cache      = (const float*)d_in[2];
    const int*   block_tables = (const int*)d_in[3];
    const int*   context_lens = (const int*)d_in[4];
    float* out = (float*)d_out;
    float* wsB = (float*)d_ws;

    sparse_attn_slice<<<B * KVH * NSL, 256, 0, stream>>>(
        q, k_cache, v_cache, block_tables, context_lens, wsB);
    sparse_attn_combine<<<B * H, 128, 0, stream>>>(wsB, out);
}